// Round 6
// baseline (61.770 us; speedup 1.0000x reference)
//
#include <hip/hip_runtime.h>

#define NROWS 500000
#define NCOLS 80
#define RPB   80                    // rows per K1 block
#define TPB   320                   // 16 rows x 20 chunks per slab
#define SLABS 5                     // 5 slabs x 16 rows = 80 rows
#define NBLK  (NROWS / RPB)         // 6250, exact
#define K0_BLOCKS 128
#define K0_TPB    256

// d_ws float layout (every cell written before read on every call)
#define WS_MAXP 0                   // [0 .. 128)      K0 per-block maxes
#define WS_PART 512                 // [512 .. 6762)   K1 per-block partials

// ---------------------------------------------------------------------------
// K0: per-block max of iou over fg rows (4 MB coalesced scan, no atomics)
// ---------------------------------------------------------------------------
__global__ void __launch_bounds__(K0_TPB)
max_kernel(const float2* __restrict__ targets, float* __restrict__ maxp) {
    unsigned tid = blockIdx.x * K0_TPB + threadIdx.x;
    unsigned stride = K0_BLOCKS * K0_TPB;
    float vmax = 0.0f;
    for (unsigned i = tid; i < (unsigned)NROWS; i += stride) {
        float2 t = targets[i];
        if ((int)t.x >= 1) vmax = fmaxf(vmax, t.y);
    }
    #pragma unroll
    for (int off = 32; off > 0; off >>= 1)
        vmax = fmaxf(vmax, __shfl_xor(vmax, off));
    __shared__ float red[K0_TPB / 64];
    int lane = threadIdx.x & 63, wid = threadIdx.x >> 6;
    if (lane == 0) red[wid] = vmax;
    __syncthreads();
    if (threadIdx.x == 0) {
        float m = 0.0f;
        #pragma unroll
        for (int w = 0; w < K0_TPB / 64; ++w) m = fmaxf(m, red[w]);
        maxp[blockIdx.x] = m;
    }
}

// ---------------------------------------------------------------------------
// K1: main stream + inline fg correction. Block b owns rows [80b, 80b+80):
// 5 slabs of 16 rows; chunk addr = b*1600 + s*320 + t (fully coalesced).
// Prologue: reduce the 128 K0 maxes (L2-broadcast) -> invM. targets for the
// 80 rows staged in LDS. Batched log: 1 v_log per float4 for the base term;
// the fg element's own log only in the rare (1-in-20 chunks) branch.
// Per-block partial to ws — no atomics, no fences.
// ---------------------------------------------------------------------------
__global__ void __launch_bounds__(TPB)
main_kernel(const float4* __restrict__ logits4,
            const float2* __restrict__ targets,
            const float* __restrict__ maxp,
            float* __restrict__ partials) {
    __shared__ float2 t2s[RPB];
    __shared__ float red[TPB / 64];
    __shared__ float s_invm;
    const unsigned t = threadIdx.x;
    const unsigned b = blockIdx.x;
    const int lane = threadIdx.x & 63, wid = threadIdx.x >> 6;

    // stage targets for this block's 80 rows
    if (t < RPB) t2s[t] = targets[b * RPB + t];

    // reduce 128 per-block maxes -> invM (threads 0..127, waves 0-1)
    {
        float m = (t < (unsigned)K0_BLOCKS) ? maxp[t] : 0.0f;
        #pragma unroll
        for (int off = 32; off > 0; off >>= 1)
            m = fmaxf(m, __shfl_xor(m, off));
        if (lane == 0) red[wid] = m;
    }
    __syncthreads();
    if (t == 0) {
        float m = fmaxf(red[0], red[1]);
        s_invm = __builtin_amdgcn_rcpf(m);
    }
    __syncthreads();
    const float invM = s_invm;

    const unsigned rl = t / 20u;             // row within slab (0..15)
    const int j0 = (int)(t - rl * 20u) * 4;  // first column of this chunk

    float acc   = 0.0f;                      // base (sp - p), scaled at end
    float acc_c = 0.0f;                      // fg corrections
    const unsigned base = b * (RPB * NCOLS / 4);
    #pragma unroll
    for (int s = 0; s < SLABS; ++s) {
        float4 x4 = logits4[base + (unsigned)s * TPB + t];
        float2 tt = t2s[s * 16 + rl];
        int   c = (int)tt.x - 1;
        float L = tt.y * invM;

        float e0 = __expf(-fabsf(x4.x)), e1 = __expf(-fabsf(x4.y));
        float e2 = __expf(-fabsf(x4.z)), e3 = __expf(-fabsf(x4.w));
        float a0 = 1.0f + e0, a1 = 1.0f + e1;
        float a2 = 1.0f + e2, a3 = 1.0f + e3;
        float r0 = __builtin_amdgcn_rcpf(a0), r1 = __builtin_amdgcn_rcpf(a1);
        float r2 = __builtin_amdgcn_rcpf(a2), r3 = __builtin_amdgcn_rcpf(a3);
        float p0 = (x4.x >= 0.0f) ? r0 : 1.0f - r0;
        float p1 = (x4.y >= 0.0f) ? r1 : 1.0f - r1;
        float p2 = (x4.z >= 0.0f) ? r2 : 1.0f - r2;
        float p3 = (x4.w >= 0.0f) ? r3 : 1.0f - r3;
        float u  = (fmaxf(x4.x, 0.0f) + fmaxf(x4.y, 0.0f))
                 + (fmaxf(x4.z, 0.0f) + fmaxf(x4.w, 0.0f));
        acc += u + __logf((a0 * a1) * (a2 * a3))
                 - ((p0 + p1) + (p2 + p3));

        int d = c - j0;
        if ((unsigned)d < 4u) {              // this chunk holds the fg elem
            float xc = x4.x, ec = e0, pc = p0;
            if (d == 1) { xc = x4.y; ec = e1; pc = p1; }
            if (d == 2) { xc = x4.z; ec = e2; pc = p2; }
            if (d == 3) { xc = x4.w; ec = e3; pc = p3; }
            float spc = fmaxf(xc, 0.0f) + __logf(1.0f + ec);
            float full;
            if (pc <= L) {
                float spn = spc - xc;        // softplus(-x)
                full = 0.25f * (spn * L + (pc - L));
            } else {
                full = 0.75f * (spc * (1.0f - L) + (L - pc));
            }
            acc_c += full - 0.75f * (spc - pc);
        }
    }

    acc = 0.75f * acc + acc_c;
    #pragma unroll
    for (int off = 32; off > 0; off >>= 1)
        acc += __shfl_xor(acc, off);
    __syncthreads();                          // red[] reuse
    if (lane == 0) red[wid] = acc;
    __syncthreads();
    if (t == 0) {
        float s = 0.0f;
        #pragma unroll
        for (int w = 0; w < TPB / 64; ++w) s += red[w];
        partials[b] = s;
    }
}

// ---------------------------------------------------------------------------
// K2: single block sums the 6250 partials -> out[0]
// ---------------------------------------------------------------------------
__global__ void final_kernel(const float* __restrict__ partials,
                             float* __restrict__ out) {
    float acc = 0.0f;
    for (unsigned i = threadIdx.x; i < (unsigned)NBLK; i += 256u)
        acc += partials[i];
    #pragma unroll
    for (int off = 32; off > 0; off >>= 1)
        acc += __shfl_xor(acc, off);
    __shared__ float red[4];
    int lane = threadIdx.x & 63, wid = threadIdx.x >> 6;
    if (lane == 0) red[wid] = acc;
    __syncthreads();
    if (threadIdx.x == 0)
        out[0] = (red[0] + red[1]) + (red[2] + red[3]);
}

extern "C" void kernel_launch(void* const* d_in, const int* in_sizes, int n_in,
                              void* d_out, int out_size, void* d_ws, size_t ws_size,
                              hipStream_t stream) {
    const float* logits  = (const float*)d_in[0];   // (N, C) f32
    const float* targets = (const float*)d_in[1];   // (N, 2) f32
    float* out = (float*)d_out;
    float* ws  = (float*)d_ws;

    max_kernel  <<<K0_BLOCKS, K0_TPB, 0, stream>>>((const float2*)targets,
                                                   ws + WS_MAXP);
    main_kernel <<<NBLK, TPB, 0, stream>>>((const float4*)logits,
                                           (const float2*)targets,
                                           ws + WS_MAXP, ws + WS_PART);
    final_kernel<<<1, 256, 0, stream>>>(ws + WS_PART, out);
}

// Round 8
// 51.402 us; speedup vs baseline: 1.2017x; 1.2017x over previous
//
#include <hip/hip_runtime.h>

#define NROWS 500000
#define NCOLS 80
#define NV (NROWS * NCOLS / 4)           // 10,000,000 float4 chunks

#define K1_BLOCKS 1250
#define K1_TPB    320
#define K1_THREADS (K1_BLOCKS * K1_TPB)  // 400,000
#define K1_ITERS  25                     // 400,000 * 25 = NV exactly

#define K2_BLOCKS 512
#define K2_TPB    256

// d_ws float layout (every cell written before read on every call)
#define WS_MAXP 0        // [0 .. 1250)    K1 per-block iou maxes
#define WS_SUM1 2048     // [2048 .. 3298) K1 per-block base sums (pre-scaled)

typedef float vfloat4 __attribute__((ext_vector_type(4)));

// ---------------------------------------------------------------------------
// K1: pure stream. (a) max iou over fg rows (2 coalesced float2 rounds),
// (b) sum of (softplus(x) - sigmoid(x)) over all 40M logits with batched log
// (1 v_log per float4). Nothing row-dependent in the hot loop. NT loads:
// logits lines are never reused (keeps targets/L3 hot for K2's gathers).
// Also zeroes out[0] for K2's atomics (kernel-boundary ordering).
// ---------------------------------------------------------------------------
__global__ void __launch_bounds__(K1_TPB)
stream_kernel(const vfloat4* __restrict__ logits4,
              const float2* __restrict__ targets,
              float* __restrict__ maxp, float* __restrict__ sump,
              float* __restrict__ out) {
    const unsigned tid = blockIdx.x * K1_TPB + threadIdx.x;
    if (tid == 0) out[0] = 0.0f;         // re-zeroed every replay

    // --- max scan of targets ---
    float vmax = 0.0f;
    {
        float2 t0 = targets[tid];                       // tid < 400000
        if ((int)t0.x >= 1) vmax = t0.y;
        unsigned i2 = tid + K1_THREADS;
        if (i2 < (unsigned)NROWS) {
            float2 t1 = targets[i2];
            if ((int)t1.x >= 1) vmax = fmaxf(vmax, t1.y);
        }
    }

    // --- base stream ---
    float acc = 0.0f;
    #pragma unroll 5
    for (int i = 0; i < K1_ITERS; ++i) {
        vfloat4 x4 = __builtin_nontemporal_load(
                        &logits4[tid + (unsigned)i * K1_THREADS]);
        float e0 = __expf(-fabsf(x4.x)), e1 = __expf(-fabsf(x4.y));
        float e2 = __expf(-fabsf(x4.z)), e3 = __expf(-fabsf(x4.w));
        float a0 = 1.0f + e0, a1 = 1.0f + e1;
        float a2 = 1.0f + e2, a3 = 1.0f + e3;
        float r0 = __builtin_amdgcn_rcpf(a0), r1 = __builtin_amdgcn_rcpf(a1);
        float r2 = __builtin_amdgcn_rcpf(a2), r3 = __builtin_amdgcn_rcpf(a3);
        float p0 = (x4.x >= 0.0f) ? r0 : 1.0f - r0;
        float p1 = (x4.y >= 0.0f) ? r1 : 1.0f - r1;
        float p2 = (x4.z >= 0.0f) ? r2 : 1.0f - r2;
        float p3 = (x4.w >= 0.0f) ? r3 : 1.0f - r3;
        float u  = (fmaxf(x4.x, 0.0f) + fmaxf(x4.y, 0.0f))
                 + (fmaxf(x4.z, 0.0f) + fmaxf(x4.w, 0.0f));
        acc += u + __logf((a0 * a1) * (a2 * a3))
                 - ((p0 + p1) + (p2 + p3));
    }

    // --- dual reduce (sum, max) ---
    #pragma unroll
    for (int off = 32; off > 0; off >>= 1) {
        acc  += __shfl_xor(acc, off);
        vmax  = fmaxf(vmax, __shfl_xor(vmax, off));
    }
    __shared__ float reds[K1_TPB / 64], redm[K1_TPB / 64];
    int lane = threadIdx.x & 63, wid = threadIdx.x >> 6;
    if (lane == 0) { reds[wid] = acc; redm[wid] = vmax; }
    __syncthreads();
    if (threadIdx.x == 0) {
        float s = 0.0f, m = 0.0f;
        #pragma unroll
        for (int w = 0; w < K1_TPB / 64; ++w) {
            s += reds[w];
            m  = fmaxf(m, redm[w]);
        }
        sump[blockIdx.x] = 0.75f * s;
        maxp[blockIdx.x] = m;
    }
}

// ---------------------------------------------------------------------------
// K2: per-block redundant max-reduce (5 KB, L2-hot) -> invM; per-fg-row
// correction  full(x_c, L) - 0.75*(sp - p)  with x_c gathered from the
// L3-resident logits; block 0 folds K1's 1250 partials; each block ends
// with one atomicAdd into out[0] (zeroed by K1).
// ---------------------------------------------------------------------------
__global__ void __launch_bounds__(K2_TPB)
corr_kernel(const float* __restrict__ logits,
            const float2* __restrict__ targets,
            const float* __restrict__ maxp,
            const float* __restrict__ sump,
            float* __restrict__ out) {
    __shared__ float red[K2_TPB / 64];
    __shared__ float sM;
    int lane = threadIdx.x & 63, wid = threadIdx.x >> 6;

    float m = 0.0f;
    for (unsigned i = threadIdx.x; i < (unsigned)K1_BLOCKS; i += K2_TPB)
        m = fmaxf(m, maxp[i]);
    #pragma unroll
    for (int off = 32; off > 0; off >>= 1)
        m = fmaxf(m, __shfl_xor(m, off));
    if (lane == 0) red[wid] = m;
    __syncthreads();
    if (threadIdx.x == 0) {
        float mm = 0.0f;
        #pragma unroll
        for (int w = 0; w < K2_TPB / 64; ++w) mm = fmaxf(mm, red[w]);
        sM = mm;
    }
    __syncthreads();
    const float invM = __builtin_amdgcn_rcpf(sM);

    float acc = 0.0f;
    if (blockIdx.x == 0) {               // fold K1 partials (1250 floats)
        for (unsigned i = threadIdx.x; i < (unsigned)K1_BLOCKS; i += K2_TPB)
            acc += sump[i];
    }

    const unsigned stride = K2_BLOCKS * K2_TPB;        // 131072
    for (unsigned r = blockIdx.x * K2_TPB + threadIdx.x;
         r < (unsigned)NROWS; r += stride) {
        float2 t = targets[r];
        int c = (int)t.x - 1;
        if (c >= 0) {
            float x  = logits[r * (unsigned)NCOLS + (unsigned)c];
            float L  = t.y * invM;
            float e  = __expf(-fabsf(x));
            float a  = 1.0f + e;
            float rr = __builtin_amdgcn_rcpf(a);
            float p  = (x >= 0.0f) ? rr : 1.0f - rr;
            float sp = fmaxf(x, 0.0f) + __logf(a);
            float full;
            if (p <= L) {
                float spn = sp - x;                    // softplus(-x)
                full = 0.25f * (spn * L + (p - L));
            } else {
                full = 0.75f * (sp * (1.0f - L) + (L - p));
            }
            acc += full - 0.75f * (sp - p);
        }
    }
    #pragma unroll
    for (int off = 32; off > 0; off >>= 1)
        acc += __shfl_xor(acc, off);
    __syncthreads();                      // red[] reuse
    if (lane == 0) red[wid] = acc;
    __syncthreads();
    if (threadIdx.x == 0) {
        float s = 0.0f;
        #pragma unroll
        for (int w = 0; w < K2_TPB / 64; ++w) s += red[w];
        atomicAdd(out, s);
    }
}

extern "C" void kernel_launch(void* const* d_in, const int* in_sizes, int n_in,
                              void* d_out, int out_size, void* d_ws, size_t ws_size,
                              hipStream_t stream) {
    const float* logits  = (const float*)d_in[0];   // (N, C) f32
    const float* targets = (const float*)d_in[1];   // (N, 2) f32
    float* out = (float*)d_out;
    float* ws  = (float*)d_ws;

    stream_kernel<<<K1_BLOCKS, K1_TPB, 0, stream>>>(
        (const vfloat4*)logits, (const float2*)targets,
        ws + WS_MAXP, ws + WS_SUM1, out);
    corr_kernel<<<K2_BLOCKS, K2_TPB, 0, stream>>>(
        logits, (const float2*)targets, ws + WS_MAXP, ws + WS_SUM1, out);
}

// Round 9
// 48.862 us; speedup vs baseline: 1.2642x; 1.0520x over previous
//
#include <hip/hip_runtime.h>

#define NROWS 500000
#define NCOLS 80
#define NV (NROWS * NCOLS / 4)           // 10,000,000 float4 chunks

#define K1_BLOCKS 1250
#define K1_TPB    320
#define K1_THREADS (K1_BLOCKS * K1_TPB)  // 400,000
#define K1_ITERS  25                     // 400,000 * 25 = NV exactly

#define K2_BLOCKS 512
#define K2_TPB    256

// d_ws float layout (every cell written before read on every call)
#define WS_MAXP 0        // [0 .. 1250)    K1 per-block iou maxes
#define WS_SUM1 2048     // [2048 .. 3298) K1 per-block base sums (pre-scaled)

// ---------------------------------------------------------------------------
// K1: pure stream. (a) max iou over fg rows (2 coalesced float2 rounds),
// (b) sum of (softplus(x) - sigmoid(x)) over all 40M logits with batched log
// (1 v_log per float4). Plain cached loads: K2's gathers NEED logits
// L3-resident (NT loads here cost ~8 us in K2 — R8 lesson).
// Also zeroes out[0] for K2's atomics (kernel-boundary ordering).
// ---------------------------------------------------------------------------
__global__ void __launch_bounds__(K1_TPB)
stream_kernel(const float4* __restrict__ logits4,
              const float2* __restrict__ targets,
              float* __restrict__ maxp, float* __restrict__ sump,
              float* __restrict__ out) {
    const unsigned tid = blockIdx.x * K1_TPB + threadIdx.x;
    if (tid == 0) out[0] = 0.0f;         // re-zeroed every replay

    // --- max scan of targets ---
    float vmax = 0.0f;
    {
        float2 t0 = targets[tid];                       // tid < 400000
        if ((int)t0.x >= 1) vmax = t0.y;
        unsigned i2 = tid + K1_THREADS;
        if (i2 < (unsigned)NROWS) {
            float2 t1 = targets[i2];
            if ((int)t1.x >= 1) vmax = fmaxf(vmax, t1.y);
        }
    }

    // --- base stream ---
    float acc = 0.0f;
    #pragma unroll 5
    for (int i = 0; i < K1_ITERS; ++i) {
        float4 x4 = logits4[tid + (unsigned)i * K1_THREADS];
        float e0 = __expf(-fabsf(x4.x)), e1 = __expf(-fabsf(x4.y));
        float e2 = __expf(-fabsf(x4.z)), e3 = __expf(-fabsf(x4.w));
        float a0 = 1.0f + e0, a1 = 1.0f + e1;
        float a2 = 1.0f + e2, a3 = 1.0f + e3;
        float r0 = __builtin_amdgcn_rcpf(a0), r1 = __builtin_amdgcn_rcpf(a1);
        float r2 = __builtin_amdgcn_rcpf(a2), r3 = __builtin_amdgcn_rcpf(a3);
        float p0 = (x4.x >= 0.0f) ? r0 : 1.0f - r0;
        float p1 = (x4.y >= 0.0f) ? r1 : 1.0f - r1;
        float p2 = (x4.z >= 0.0f) ? r2 : 1.0f - r2;
        float p3 = (x4.w >= 0.0f) ? r3 : 1.0f - r3;
        float u  = (fmaxf(x4.x, 0.0f) + fmaxf(x4.y, 0.0f))
                 + (fmaxf(x4.z, 0.0f) + fmaxf(x4.w, 0.0f));
        acc += u + __logf((a0 * a1) * (a2 * a3))
                 - ((p0 + p1) + (p2 + p3));
    }

    // --- dual reduce (sum, max) ---
    #pragma unroll
    for (int off = 32; off > 0; off >>= 1) {
        acc  += __shfl_xor(acc, off);
        vmax  = fmaxf(vmax, __shfl_xor(vmax, off));
    }
    __shared__ float reds[K1_TPB / 64], redm[K1_TPB / 64];
    int lane = threadIdx.x & 63, wid = threadIdx.x >> 6;
    if (lane == 0) { reds[wid] = acc; redm[wid] = vmax; }
    __syncthreads();
    if (threadIdx.x == 0) {
        float s = 0.0f, m = 0.0f;
        #pragma unroll
        for (int w = 0; w < K1_TPB / 64; ++w) {
            s += reds[w];
            m  = fmaxf(m, redm[w]);
        }
        sump[blockIdx.x] = 0.75f * s;
        maxp[blockIdx.x] = m;
    }
}

// ---------------------------------------------------------------------------
// K2: per-block redundant max-reduce (5 KB, L2-hot) -> invM; per-fg-row
// correction  full(x_c, L) - 0.75*(sp - p)  with x_c gathered from the
// L3-resident logits; block 0 folds K1's 1250 partials; each block ends
// with one atomicAdd into out[0] (zeroed by K1).
// ---------------------------------------------------------------------------
__global__ void __launch_bounds__(K2_TPB)
corr_kernel(const float* __restrict__ logits,
            const float2* __restrict__ targets,
            const float* __restrict__ maxp,
            const float* __restrict__ sump,
            float* __restrict__ out) {
    __shared__ float red[K2_TPB / 64];
    __shared__ float sM;
    int lane = threadIdx.x & 63, wid = threadIdx.x >> 6;

    float m = 0.0f;
    for (unsigned i = threadIdx.x; i < (unsigned)K1_BLOCKS; i += K2_TPB)
        m = fmaxf(m, maxp[i]);
    #pragma unroll
    for (int off = 32; off > 0; off >>= 1)
        m = fmaxf(m, __shfl_xor(m, off));
    if (lane == 0) red[wid] = m;
    __syncthreads();
    if (threadIdx.x == 0) {
        float mm = 0.0f;
        #pragma unroll
        for (int w = 0; w < K2_TPB / 64; ++w) mm = fmaxf(mm, red[w]);
        sM = mm;
    }
    __syncthreads();
    const float invM = __builtin_amdgcn_rcpf(sM);

    float acc = 0.0f;
    if (blockIdx.x == 0) {               // fold K1 partials (1250 floats)
        for (unsigned i = threadIdx.x; i < (unsigned)K1_BLOCKS; i += K2_TPB)
            acc += sump[i];
    }

    const unsigned stride = K2_BLOCKS * K2_TPB;        // 131072
    for (unsigned r = blockIdx.x * K2_TPB + threadIdx.x;
         r < (unsigned)NROWS; r += stride) {
        float2 t = targets[r];
        int c = (int)t.x - 1;
        if (c >= 0) {
            float x  = logits[r * (unsigned)NCOLS + (unsigned)c];
            float L  = t.y * invM;
            float e  = __expf(-fabsf(x));
            float a  = 1.0f + e;
            float rr = __builtin_amdgcn_rcpf(a);
            float p  = (x >= 0.0f) ? rr : 1.0f - rr;
            float sp = fmaxf(x, 0.0f) + __logf(a);
            float full;
            if (p <= L) {
                float spn = sp - x;                    // softplus(-x)
                full = 0.25f * (spn * L + (p - L));
            } else {
                full = 0.75f * (sp * (1.0f - L) + (L - p));
            }
            acc += full - 0.75f * (sp - p);
        }
    }
    #pragma unroll
    for (int off = 32; off > 0; off >>= 1)
        acc += __shfl_xor(acc, off);
    __syncthreads();                      // red[] reuse
    if (lane == 0) red[wid] = acc;
    __syncthreads();
    if (threadIdx.x == 0) {
        float s = 0.0f;
        #pragma unroll
        for (int w = 0; w < K2_TPB / 64; ++w) s += red[w];
        atomicAdd(out, s);
    }
}

extern "C" void kernel_launch(void* const* d_in, const int* in_sizes, int n_in,
                              void* d_out, int out_size, void* d_ws, size_t ws_size,
                              hipStream_t stream) {
    const float* logits  = (const float*)d_in[0];   // (N, C) f32
    const float* targets = (const float*)d_in[1];   // (N, 2) f32
    float* out = (float*)d_out;
    float* ws  = (float*)d_ws;

    stream_kernel<<<K1_BLOCKS, K1_TPB, 0, stream>>>(
        (const float4*)logits, (const float2*)targets,
        ws + WS_MAXP, ws + WS_SUM1, out);
    corr_kernel<<<K2_BLOCKS, K2_TPB, 0, stream>>>(
        logits, (const float2*)targets, ws + WS_MAXP, ws + WS_SUM1, out);
}